// Round 6
// baseline (391.883 us; speedup 1.0000x reference)
//
#include <hip/hip_runtime.h>
#include <hip/hip_bf16.h>
#include <stdint.h>

#define M_DIM 8192
#define N_DIM 4096
#define K_DIM 4096
#define RANK  16

#define BM 256
#define BN 256
#define BK 64
#define NKT (K_DIM / BK)   // 64 K-tiles

typedef __attribute__((ext_vector_type(8)))  __bf16 bf16x8;
typedef __attribute__((ext_vector_type(16))) float  f32x16;
typedef __attribute__((ext_vector_type(8)))  unsigned short u16x8;

__device__ __forceinline__ unsigned short f2bf(float f) {
    union { float f; uint32_t u; } c; c.f = f;
    uint32_t b = c.u;
    b += 0x7FFFu + ((b >> 16) & 1u);   // RNE (finite data)
    return (unsigned short)(b >> 16);
}

// ---------------- fused prep ----------------
#define WEFF_BLOCKS 1024   // (4096/32) * (4096/512)
#define CONV_BLOCKS 2048
__global__ __launch_bounds__(256) void prep_kernel(
    const float* __restrict__ x,
    const float* __restrict__ wp,   // [4096][1024]
    const float* __restrict__ lA,   // [16][4096]
    const float* __restrict__ lB,   // [4096][16]
    const int*   __restrict__ scaling,
    unsigned short* __restrict__ xb,     // [8192][4096] bf16
    unsigned short* __restrict__ weff) { // [4096][4096] bf16
    __shared__ float lAs[16][512];       // 32 KiB
    const int t = threadIdx.x;
    if (blockIdx.x < WEFF_BLOCKS) {
        const int bo = blockIdx.x >> 3;        // row tile of 32
        const int bi = blockIdx.x & 7;         // col tile of 512
#pragma unroll
        for (int v = 0; v < 8; ++v) {
            int idx = v * 256 + t;
            int r = idx >> 7;
            int c4 = idx & 127;
            reinterpret_cast<float4*>(&lAs[r][0])[c4] =
                reinterpret_cast<const float4*>(lA + (size_t)r * 4096 + bi * 512)[c4];
        }
        __syncthreads();
        const int row = t >> 3;
        const int o = bo * 32 + row;
        const float s = (float)scaling[0];
        float b[RANK];
#pragma unroll
        for (int r = 0; r < RANK; ++r) b[r] = lB[o * RANK + r] * s;
        const float* wrow = wp + (size_t)o * 1024;
        const int cbase = (t & 7) * 4;
#pragma unroll
        for (int j = 0; j < 16; ++j) {
            int c = cbase + j * 32;
            int gi = bi * 512 + c;
            float4 w = *reinterpret_cast<const float4*>(wrow + (gi & 1023));
            float a0 = w.x, a1 = w.y, a2 = w.z, a3 = w.w;
#pragma unroll
            for (int r = 0; r < RANK; ++r) {
                float4 la = *reinterpret_cast<const float4*>(&lAs[r][c]);
                a0 = fmaf(b[r], la.x, a0);
                a1 = fmaf(b[r], la.y, a1);
                a2 = fmaf(b[r], la.z, a2);
                a3 = fmaf(b[r], la.w, a3);
            }
            ushort4 ov;
            ov.x = f2bf(a0); ov.y = f2bf(a1); ov.z = f2bf(a2); ov.w = f2bf(a3);
            *reinterpret_cast<ushort4*>(weff + (size_t)o * 4096 + gi) = ov;
        }
    } else {
        const int n8 = (M_DIM * K_DIM) / 8;
        int idx = (blockIdx.x - WEFF_BLOCKS) * 256 + t;
        const int stride = CONV_BLOCKS * 256;
        for (int i = idx; i < n8; i += stride) {
            float4 v0 = reinterpret_cast<const float4*>(x)[2 * i];
            float4 v1 = reinterpret_cast<const float4*>(x)[2 * i + 1];
            u16x8 o;
            o[0] = f2bf(v0.x); o[1] = f2bf(v0.y); o[2] = f2bf(v0.z); o[3] = f2bf(v0.w);
            o[4] = f2bf(v1.x); o[5] = f2bf(v1.y); o[6] = f2bf(v1.z); o[7] = f2bf(v1.w);
            reinterpret_cast<u16x8*>(xb)[i] = o;
        }
    }
}

// ---------------- 256x256 8-phase bf16 GEMM, 32x32x16, fragment-order LDS ----------------
// LDS per buf (64 KiB): A frags [mt 0..7][kc 0..3] of 1 KiB (lane l: row mt*32+(l&31),
// k kt*64+kc*16+(l>>5)*8), then B frags [nt 0..7][kc 0..3] likewise (cols).
// All ds_reads are base + lane*16 (linear, conflict-free). Stage regions:
//   A-mh = { mt in {2mh, 2mh+1, 2mh+4, 2mh+5} }  (read by quad(mh,*) across wr)
//   B-nh = { nt === nh (mod 2) }                 (read by quad(*,nh) across wc)
// Schedule/vmcnt identical to the round-5-verified table.

template<int MH, int NH>
__device__ __forceinline__ void mfma_quad(const bf16x8 (&a)[2][4], const bf16x8 (&b)[4],
                                          f32x16 (&acc)[4][2]) {
#pragma unroll
    for (int kc = 0; kc < 4; ++kc)
#pragma unroll
        for (int mti = 0; mti < 2; ++mti)
            acc[MH * 2 + mti][NH] = __builtin_amdgcn_mfma_f32_32x32x16_bf16(
                a[mti][kc], b[kc], acc[MH * 2 + mti][NH], 0, 0, 0);
}

__global__ __launch_bounds__(512, 1) void gemm_kernel(
    const unsigned short* __restrict__ A,   // x bf16 [8192][4096]
    const unsigned short* __restrict__ B,   // W_eff bf16 [4096][4096]
    float* __restrict__ C)                  // [8192][4096] fp32
{
    __shared__ __align__(16) char lds[131072];

    const int tid  = threadIdx.x;
    const int lane = tid & 63;
    const int w    = tid >> 6;
    const int wr = w >> 2;             // 0..1 (M)
    const int wc = w & 3;              // 0..3 (N)

    // bijective XCD swizzle: 512 blocks, 8 XCDs
    const int bid = blockIdx.x;
    const int swz = (bid & 7) * 64 + (bid >> 3);
    const int bm = swz >> 4;
    const int bn = swz & 15;
    const int m0 = bm * BM;
    const int n0 = bn * BN;

    // per-lane staging source bases (fragment order)
    const unsigned short* Asrc = A + (size_t)(m0 + (lane & 31)) * K_DIM + (lane >> 5) * 8;
    const unsigned short* Bsrc = B + (size_t)(n0 + (lane & 31)) * K_DIM + (lane >> 5) * 8;

    // STAGE_A(buf,mh,kt): 2 gloads; frag f = j*8+w, q=f>>2, kc=f&3,
    //   mt = mh*2 + (q&1) + (q>>1)*4
#define STAGE_A(buf, mh, kt) do { \
    _Pragma("unroll") for (int j = 0; j < 2; ++j) { \
        const int f_ = j * 8 + w, q_ = f_ >> 2, kc_ = f_ & 3; \
        const int mt_ = (mh) * 2 + (q_ & 1) + (q_ >> 1) * 4; \
        __builtin_amdgcn_global_load_lds( \
            (const __attribute__((address_space(1))) void*)(Asrc + (size_t)(mt_ * 32) * K_DIM + (kt) * 64 + kc_ * 16), \
            (__attribute__((address_space(3))) void*)(lds + (buf) * 65536 + mt_ * 4096 + kc_ * 1024), 16, 0, 0); \
    } \
} while (0)

    // STAGE_B(buf,nh,kt): frag f = j*8+w, q=f>>2, kc=f&3, nt = 2*q + nh
#define STAGE_B(buf, nh, kt) do { \
    _Pragma("unroll") for (int j = 0; j < 2; ++j) { \
        const int f_ = j * 8 + w, q_ = f_ >> 2, kc_ = f_ & 3; \
        const int nt_ = 2 * q_ + (nh); \
        __builtin_amdgcn_global_load_lds( \
            (const __attribute__((address_space(1))) void*)(Bsrc + (size_t)(nt_ * 32) * K_DIM + (kt) * 64 + kc_ * 16), \
            (__attribute__((address_space(3))) void*)(lds + (buf) * 65536 + 32768 + nt_ * 4096 + kc_ * 1024), 16, 0, 0); \
    } \
} while (0)

    const int lb = lane * 16;          // linear lane byte offset within a frag
    const int wr4 = wr * 4;
    const int wc2 = wc * 2;

#define RD_A(dst, buf, mh) do { \
    _Pragma("unroll") for (int mti = 0; mti < 2; ++mti) \
    _Pragma("unroll") for (int kc = 0; kc < 4; ++kc) \
        dst[mti][kc] = *(const bf16x8*)(lds + (buf) * 65536 + (wr4 + (mh) * 2 + mti) * 4096 + kc * 1024 + lb); \
} while (0)

#define RD_B(dst, buf, nh) do { \
    _Pragma("unroll") for (int kc = 0; kc < 4; ++kc) \
        dst[kc] = *(const bf16x8*)(lds + (buf) * 65536 + 32768 + (wc2 + (nh)) * 4096 + kc * 1024 + lb); \
} while (0)

#define PH_TAIL(QUAD) \
    __builtin_amdgcn_s_barrier(); \
    asm volatile("s_waitcnt lgkmcnt(0)" ::: "memory"); \
    __builtin_amdgcn_s_setprio(1); \
    QUAD; \
    __builtin_amdgcn_s_setprio(0);

    f32x16 acc[4][2];
#pragma unroll
    for (int i = 0; i < 4; ++i)
#pragma unroll
        for (int j = 0; j < 2; ++j)
#pragma unroll
            for (int r = 0; r < 16; ++r) acc[i][j][r] = 0.f;

    bf16x8 afr[2][4];        // current mh-half A frags
    bf16x8 b0[4], b1[4];     // register-held B frags (live across phases)

    // ---- prologue: tile0 (A0,B1,A1,B0) + tile1 (A0,B1) ----
    STAGE_A(0, 0, 0); STAGE_B(0, 1, 0); STAGE_A(0, 1, 0); STAGE_B(0, 0, 0);
    STAGE_A(1, 0, 1); STAGE_B(1, 1, 1);
    asm volatile("s_waitcnt vmcnt(4)" ::: "memory");
    __builtin_amdgcn_s_barrier();

    for (int it = 0; it < NKT / 2; ++it) {
        const int k1 = 2 * it + 1;
        const int k2 = (2 * it + 2) & (NKT - 1);   // dummy re-stage on last iter (safe)
        const int k3 = (2 * it + 3) & (NKT - 1);

        // P1: buf0 quad(0,0)
        RD_A(afr, 0, 0); RD_B(b0, 0, 0);
        STAGE_A(1, 1, k1);
        asm volatile("s_waitcnt lgkmcnt(8)" ::: "memory");
        PH_TAIL((mfma_quad<0, 0>(afr, b0, acc)));
        // P2: buf0 quad(0,1)
        RD_B(b1, 0, 1);
        STAGE_B(1, 0, k1);
        PH_TAIL((mfma_quad<0, 1>(afr, b1, acc)));
        // P3: buf0 quad(1,1)
        RD_A(afr, 0, 1);
        STAGE_A(0, 0, k2);
        PH_TAIL((mfma_quad<1, 1>(afr, b1, acc)));
        // P4: buf0 quad(1,0) — read-free; counted vmcnt + barrier (buf1-k1 landed)
        STAGE_B(0, 1, k2);
        PH_TAIL((mfma_quad<1, 0>(afr, b0, acc)));
        asm volatile("s_waitcnt vmcnt(4)" ::: "memory");
        __builtin_amdgcn_s_barrier();
        // P5: buf1 quad(0,0)
        RD_A(afr, 1, 0); RD_B(b0, 1, 0);
        STAGE_A(0, 1, k2);
        asm volatile("s_waitcnt lgkmcnt(8)" ::: "memory");
        PH_TAIL((mfma_quad<0, 0>(afr, b0, acc)));
        // P6: buf1 quad(0,1)
        RD_B(b1, 1, 1);
        STAGE_B(0, 0, k2);
        PH_TAIL((mfma_quad<0, 1>(afr, b1, acc)));
        // P7: buf1 quad(1,1)
        RD_A(afr, 1, 1);
        STAGE_A(1, 0, k3);
        PH_TAIL((mfma_quad<1, 1>(afr, b1, acc)));
        // P8: buf1 quad(1,0) — read-free; counted vmcnt + barrier (buf0-k2 landed)
        STAGE_B(1, 1, k3);
        PH_TAIL((mfma_quad<1, 0>(afr, b0, acc)));
        asm volatile("s_waitcnt vmcnt(4)" ::: "memory");
        __builtin_amdgcn_s_barrier();
    }

    // ---- epilogue: direct stores. 32x32 D frag (m74/m101, verified in round 3):
    // col = lane&31, row = (reg&3) + 8*(reg>>2) + 4*(lane>>5)
    const int crow = m0 + wr * 128 + 4 * (lane >> 5);
    const int ccol = n0 + wc * 64 + (lane & 31);
#pragma unroll
    for (int mt = 0; mt < 4; ++mt)
#pragma unroll
        for (int nt = 0; nt < 2; ++nt)
#pragma unroll
            for (int r = 0; r < 16; ++r)
                C[(size_t)(crow + mt * 32 + (r & 3) + 8 * (r >> 2)) * N_DIM + ccol + nt * 32] =
                    acc[mt][nt][r];

#undef STAGE_A
#undef STAGE_B
#undef RD_A
#undef RD_B
#undef PH_TAIL
}

extern "C" void kernel_launch(void* const* d_in, const int* in_sizes, int n_in,
                              void* d_out, int out_size, void* d_ws, size_t ws_size,
                              hipStream_t stream) {
    const float* x  = (const float*)d_in[0];
    const float* wp = (const float*)d_in[1];
    const float* lA = (const float*)d_in[2];
    const float* lB = (const float*)d_in[3];
    const int*   sc = (const int*)d_in[4];
    float* out = (float*)d_out;

    unsigned short* xb   = (unsigned short*)d_ws;                               // 64 MB
    unsigned short* weff = (unsigned short*)d_ws + (size_t)M_DIM * K_DIM;       // 32 MB

    prep_kernel<<<WEFF_BLOCKS + CONV_BLOCKS, 256, 0, stream>>>(x, wp, lA, lB, sc, xb, weff);

    int grid = (M_DIM / BM) * (N_DIM / BN);   // 32 * 16 = 512
    gemm_kernel<<<grid, 512, 0, stream>>>(xb, weff, out);
}

// Round 7
// 279.799 us; speedup vs baseline: 1.4006x; 1.4006x over previous
//
#include <hip/hip_runtime.h>
#include <hip/hip_bf16.h>
#include <stdint.h>

#define M_DIM 8192
#define N_DIM 4096
#define K_DIM 4096
#define RANK  16

#define BM 256
#define BN 256
#define BK 64
#define NKT (K_DIM / BK)   // 64 K-tiles

typedef __attribute__((ext_vector_type(8))) __bf16 bf16x8;
typedef __attribute__((ext_vector_type(4))) float  f32x4;
typedef __attribute__((ext_vector_type(8))) unsigned short u16x8;

__device__ __forceinline__ unsigned short f2bf(float f) {
    union { float f; uint32_t u; } c; c.f = f;
    uint32_t b = c.u;
    b += 0x7FFFu + ((b >> 16) & 1u);   // RNE (finite data)
    return (unsigned short)(b >> 16);
}

// ---------------- fused prep ----------------
#define WEFF_BLOCKS 1024   // (4096/32) * (4096/512)
#define CONV_BLOCKS 2048
__global__ __launch_bounds__(256) void prep_kernel(
    const float* __restrict__ x,
    const float* __restrict__ wp,   // [4096][1024]
    const float* __restrict__ lA,   // [16][4096]
    const float* __restrict__ lB,   // [4096][16]
    const int*   __restrict__ scaling,
    unsigned short* __restrict__ xb,     // [8192][4096] bf16
    unsigned short* __restrict__ weff) { // [4096][4096] bf16
    __shared__ float lAs[16][512];       // 32 KiB
    const int t = threadIdx.x;
    if (blockIdx.x < WEFF_BLOCKS) {
        const int bo = blockIdx.x >> 3;        // row tile of 32
        const int bi = blockIdx.x & 7;         // col tile of 512
#pragma unroll
        for (int v = 0; v < 8; ++v) {
            int idx = v * 256 + t;
            int r = idx >> 7;
            int c4 = idx & 127;
            reinterpret_cast<float4*>(&lAs[r][0])[c4] =
                reinterpret_cast<const float4*>(lA + (size_t)r * 4096 + bi * 512)[c4];
        }
        __syncthreads();
        const int row = t >> 3;
        const int o = bo * 32 + row;
        const float s = (float)scaling[0];
        float b[RANK];
#pragma unroll
        for (int r = 0; r < RANK; ++r) b[r] = lB[o * RANK + r] * s;
        const float* wrow = wp + (size_t)o * 1024;
        const int cbase = (t & 7) * 4;
#pragma unroll
        for (int j = 0; j < 16; ++j) {
            int c = cbase + j * 32;
            int gi = bi * 512 + c;
            float4 w = *reinterpret_cast<const float4*>(wrow + (gi & 1023));
            float a0 = w.x, a1 = w.y, a2 = w.z, a3 = w.w;
#pragma unroll
            for (int r = 0; r < RANK; ++r) {
                float4 la = *reinterpret_cast<const float4*>(&lAs[r][c]);
                a0 = fmaf(b[r], la.x, a0);
                a1 = fmaf(b[r], la.y, a1);
                a2 = fmaf(b[r], la.z, a2);
                a3 = fmaf(b[r], la.w, a3);
            }
            ushort4 ov;
            ov.x = f2bf(a0); ov.y = f2bf(a1); ov.z = f2bf(a2); ov.w = f2bf(a3);
            *reinterpret_cast<ushort4*>(weff + (size_t)o * 4096 + gi) = ov;
        }
    } else {
        const int n8 = (M_DIM * K_DIM) / 8;
        int idx = (blockIdx.x - WEFF_BLOCKS) * 256 + t;
        const int stride = CONV_BLOCKS * 256;
        for (int i = idx; i < n8; i += stride) {
            float4 v0 = reinterpret_cast<const float4*>(x)[2 * i];
            float4 v1 = reinterpret_cast<const float4*>(x)[2 * i + 1];
            u16x8 o;
            o[0] = f2bf(v0.x); o[1] = f2bf(v0.y); o[2] = f2bf(v0.z); o[3] = f2bf(v0.w);
            o[4] = f2bf(v1.x); o[5] = f2bf(v1.y); o[6] = f2bf(v1.z); o[7] = f2bf(v1.w);
            reinterpret_cast<u16x8*>(xb)[i] = o;
        }
    }
}

// ---------------- 256x256 8-phase bf16 GEMM, m201-style deep pipeline ----------------
// 1-gap staging (stage each half-region one phase after its only read) + trailing
// barrier per phase (required: separates readers' lgkm-drain from stagers' DMA) +
// vmcnt(6) at P4/P8 (3 half-stages in flight).  Hazard table verified:
//   frees: b0A0@P1 b0B0@P1 b0B1@P2 b0A1@P3 b1A0@P5 b1B0@P5 b1B1@P6 b1A1@P7
//   stages: P1:b1A1(o) P2:b0A0(e+2) P3:b0B0(e+2) P4:b0B1(e+2) P5:b0A1(e+2)
//           P6:b1A0(o+2) P7:b1B0(o+2) P8:b1B1(o+2)
//   vmcnt(6)@P4 drains {P6p,P7p,P8p,P1} = buf1-o complete; @P8 drains
//   {P2..P5} = buf0-(e+2) complete.  16x16x32 MFMA, reg-held B frags,
//   (row&7)<<4 involution swizzle (pre-swizzled global source + swizzled read).

template<int MH, int NH>
__device__ __forceinline__ void mfma_quad(const bf16x8 (&a)[4][2], const bf16x8 (&b)[2][2],
                                          f32x4 (&acc)[8][4]) {
#pragma unroll
    for (int kc = 0; kc < 2; ++kc)
#pragma unroll
        for (int mf = 0; mf < 4; ++mf)
#pragma unroll
            for (int nf = 0; nf < 2; ++nf)
                acc[MH * 4 + mf][NH * 2 + nf] = __builtin_amdgcn_mfma_f32_16x16x32_bf16(
                    a[mf][kc], b[nf][kc], acc[MH * 4 + mf][NH * 2 + nf], 0, 0, 0);
}

__global__ __launch_bounds__(512, 1) void gemm_kernel(
    const unsigned short* __restrict__ A,   // x bf16 [8192][4096]
    const unsigned short* __restrict__ B,   // W_eff bf16 [4096][4096]
    float* __restrict__ C)                  // [8192][4096] fp32
{
    __shared__ __align__(16) char lds[131072];

    const int tid  = threadIdx.x;
    const int lane = tid & 63;
    const int wave = tid >> 6;
    const int wr = wave >> 2;          // 0..1 (M)
    const int wc = wave & 3;           // 0..3 (N)

    // bijective XCD swizzle: 512 blocks, 8 XCDs
    const int bid = blockIdx.x;
    const int swz = (bid & 7) * 64 + (bid >> 3);
    const int bm = swz >> 4;
    const int bn = swz & 15;
    const int m0 = bm * BM;
    const int n0 = bn * BN;

    // ---- staging addressing (coalesced; pre-swizzled source col) ----
    const int srccol = 8 * ((tid & 7) ^ ((tid >> 3) & 7));
    const int wub    = (tid & ~63) * 16;                     // wave-uniform LDS byte base
    const unsigned short* Ag = A + (size_t)(m0 + (tid >> 3)) * K_DIM + srccol;
    const unsigned short* Bg = B + (size_t)(n0 + (tid >> 8) * 64 + ((tid >> 3) & 31)) * K_DIM + srccol;

#define STAGE_A(buf, mh, kt) do { \
    __builtin_amdgcn_global_load_lds( \
        (const __attribute__((address_space(1))) void*)(Ag + (size_t)((mh) * 64) * K_DIM + (size_t)(kt) * 64), \
        (__attribute__((address_space(3))) void*)(lds + (buf) * 65536 + (mh) * 16384 + wub), 16, 0, 0); \
    __builtin_amdgcn_global_load_lds( \
        (const __attribute__((address_space(1))) void*)(Ag + (size_t)(128 + (mh) * 64) * K_DIM + (size_t)(kt) * 64), \
        (__attribute__((address_space(3))) void*)(lds + (buf) * 65536 + (mh) * 16384 + 8192 + wub), 16, 0, 0); \
} while (0)

#define STAGE_B(buf, nh, kt) do { \
    __builtin_amdgcn_global_load_lds( \
        (const __attribute__((address_space(1))) void*)(Bg + (size_t)((nh) * 32) * K_DIM + (size_t)(kt) * 64), \
        (__attribute__((address_space(3))) void*)(lds + (buf) * 65536 + 32768 + (nh) * 16384 + wub), 16, 0, 0); \
    __builtin_amdgcn_global_load_lds( \
        (const __attribute__((address_space(1))) void*)(Bg + (size_t)(128 + (nh) * 32) * K_DIM + (size_t)(kt) * 64), \
        (__attribute__((address_space(3))) void*)(lds + (buf) * 65536 + 32768 + (nh) * 16384 + 8192 + wub), 16, 0, 0); \
} while (0)

    // ---- read-side addressing (16x16x32 frags) ----
    const int wrA   = wr * 8192;
    const int wcB   = wc * 4096;
    const int rdrow = (lane & 15) * 128;           // row byte offset
    const int rdxor = (lane & 7) << 4;             // swizzle XOR (row&7)<<4
    const int rdg   = (lane >> 4) * 16;            // 16B slot

#define RD_A(dst, buf, mh) do { \
    _Pragma("unroll") for (int mf = 0; mf < 4; ++mf) \
    _Pragma("unroll") for (int kc = 0; kc < 2; ++kc) \
        dst[mf][kc] = *(const bf16x8*)(lds + (buf) * 65536 + (mh) * 16384 + wrA + rdrow + mf * 2048 + ((kc * 64 + rdg) ^ rdxor)); \
} while (0)

#define RD_B(dst, buf, nh) do { \
    _Pragma("unroll") for (int nf = 0; nf < 2; ++nf) \
    _Pragma("unroll") for (int kc = 0; kc < 2; ++kc) \
        dst[nf][kc] = *(const bf16x8*)(lds + (buf) * 65536 + 32768 + (nh) * 16384 + wcB + rdrow + nf * 2048 + ((kc * 64 + rdg) ^ rdxor)); \
} while (0)

#define PH(QUAD) \
    __builtin_amdgcn_s_barrier(); \
    asm volatile("s_waitcnt lgkmcnt(0)" ::: "memory"); \
    __builtin_amdgcn_s_setprio(1); \
    QUAD; \
    __builtin_amdgcn_s_setprio(0); \
    __builtin_amdgcn_s_barrier();

#define PH_V(QUAD) \
    __builtin_amdgcn_s_barrier(); \
    asm volatile("s_waitcnt lgkmcnt(0)" ::: "memory"); \
    __builtin_amdgcn_s_setprio(1); \
    QUAD; \
    __builtin_amdgcn_s_setprio(0); \
    asm volatile("s_waitcnt vmcnt(6)" ::: "memory"); \
    __builtin_amdgcn_s_barrier();

    f32x4 acc[8][4];
#pragma unroll
    for (int i = 0; i < 8; ++i)
#pragma unroll
        for (int j = 0; j < 4; ++j) acc[i][j] = (f32x4){0.f, 0.f, 0.f, 0.f};

    bf16x8 afr[4][2];
    bf16x8 b0[2][2], b1[2][2];   // register-held B frags

    // ---- prologue: buf0(tile0) complete first, then buf1(tile1) A0,B0,B1 ----
    STAGE_A(0, 0, 0); STAGE_B(0, 0, 0); STAGE_B(0, 1, 0); STAGE_A(0, 1, 0);
    STAGE_A(1, 0, 1); STAGE_B(1, 0, 1); STAGE_B(1, 1, 1);
    asm volatile("s_waitcnt vmcnt(6)" ::: "memory");   // buf0-tile0 landed
    __builtin_amdgcn_s_barrier();

    for (int it = 0; it < NKT / 2; ++it) {
        const int o  = 2 * it + 1;
        const int e2 = (2 * it + 2) & (NKT - 1);   // dummy re-stage on last iter (safe)
        const int o2 = (2 * it + 3) & (NKT - 1);

        // P1: buf0 quad(0,0); stage b1A1(o)
        RD_A(afr, 0, 0); RD_B(b0, 0, 0);
        STAGE_A(1, 1, o);
        asm volatile("s_waitcnt lgkmcnt(8)" ::: "memory");
        PH((mfma_quad<0, 0>(afr, b0, acc)));
        // P2: buf0 quad(0,1); stage b0A0(e+2)
        RD_B(b1, 0, 1);
        STAGE_A(0, 0, e2);
        PH((mfma_quad<0, 1>(afr, b1, acc)));
        // P3: buf0 quad(1,1); stage b0B0(e+2)
        RD_A(afr, 0, 1);
        STAGE_B(0, 0, e2);
        PH((mfma_quad<1, 1>(afr, b1, acc)));
        // P4: buf0 quad(1,0); stage b0B1(e+2); vmcnt(6) -> buf1-o complete
        STAGE_B(0, 1, e2);
        PH_V((mfma_quad<1, 0>(afr, b0, acc)));
        // P5: buf1 quad(0,0); stage b0A1(e+2)
        RD_A(afr, 1, 0); RD_B(b0, 1, 0);
        STAGE_A(0, 1, e2);
        asm volatile("s_waitcnt lgkmcnt(8)" ::: "memory");
        PH((mfma_quad<0, 0>(afr, b0, acc)));
        // P6: buf1 quad(0,1); stage b1A0(o+2)
        RD_B(b1, 1, 1);
        STAGE_A(1, 0, o2);
        PH((mfma_quad<0, 1>(afr, b1, acc)));
        // P7: buf1 quad(1,1); stage b1B0(o+2)
        RD_A(afr, 1, 1);
        STAGE_B(1, 0, o2);
        PH((mfma_quad<1, 1>(afr, b1, acc)));
        // P8: buf1 quad(1,0); stage b1B1(o+2); vmcnt(6) -> buf0-(e+2) complete
        STAGE_B(1, 1, o2);
        PH_V((mfma_quad<1, 0>(afr, b0, acc)));
    }

    // ---- epilogue: direct stores. D frag: col = lane&15, row = (lane>>4)*4 + r ----
    const int crow = m0 + wr * 128 + (lane >> 4) * 4;
    const int ccol = n0 + wc * 64 + (lane & 15);
#pragma unroll
    for (int mi = 0; mi < 8; ++mi)
#pragma unroll
        for (int ni = 0; ni < 4; ++ni)
#pragma unroll
            for (int r = 0; r < 4; ++r)
                C[(size_t)(crow + mi * 16 + r) * N_DIM + ccol + ni * 16] = acc[mi][ni][r];

#undef STAGE_A
#undef STAGE_B
#undef RD_A
#undef RD_B
#undef PH
#undef PH_V
}

extern "C" void kernel_launch(void* const* d_in, const int* in_sizes, int n_in,
                              void* d_out, int out_size, void* d_ws, size_t ws_size,
                              hipStream_t stream) {
    const float* x  = (const float*)d_in[0];
    const float* wp = (const float*)d_in[1];
    const float* lA = (const float*)d_in[2];
    const float* lB = (const float*)d_in[3];
    const int*   sc = (const int*)d_in[4];
    float* out = (float*)d_out;

    unsigned short* xb   = (unsigned short*)d_ws;                               // 64 MB
    unsigned short* weff = (unsigned short*)d_ws + (size_t)M_DIM * K_DIM;       // 32 MB

    prep_kernel<<<WEFF_BLOCKS + CONV_BLOCKS, 256, 0, stream>>>(x, wp, lA, lB, sc, xb, weff);

    int grid = (M_DIM / BM) * (N_DIM / BN);   // 32 * 16 = 512
    gemm_kernel<<<grid, 512, 0, stream>>>(xb, weff, out);
}

// Round 8
// 270.420 us; speedup vs baseline: 1.4492x; 1.0347x over previous
//
#include <hip/hip_runtime.h>
#include <hip/hip_bf16.h>
#include <stdint.h>

#define M_DIM 8192
#define N_DIM 4096
#define K_DIM 4096
#define RANK  16

#define BM 256
#define BN 256
#define BK 64
#define NKT (K_DIM / BK)   // 64 K-tiles

typedef __attribute__((ext_vector_type(8))) __bf16 bf16x8;
typedef __attribute__((ext_vector_type(4))) float  f32x4;
typedef __attribute__((ext_vector_type(8))) unsigned short u16x8;

__device__ __forceinline__ unsigned short f2bf(float f) {
    union { float f; uint32_t u; } c; c.f = f;
    uint32_t b = c.u;
    b += 0x7FFFu + ((b >> 16) & 1u);   // RNE (finite data)
    return (unsigned short)(b >> 16);
}

// ---------------- fused prep ----------------
#define WEFF_BLOCKS 1024   // (4096/32) * (4096/512)
#define CONV_BLOCKS 2048
__global__ __launch_bounds__(256) void prep_kernel(
    const float* __restrict__ x,
    const float* __restrict__ wp,   // [4096][1024]
    const float* __restrict__ lA,   // [16][4096]
    const float* __restrict__ lB,   // [4096][16]
    const int*   __restrict__ scaling,
    unsigned short* __restrict__ xb,     // [8192][4096] bf16
    unsigned short* __restrict__ weff) { // [4096][4096] bf16
    __shared__ float lAs[16][512];       // 32 KiB
    const int t = threadIdx.x;
    if (blockIdx.x < WEFF_BLOCKS) {
        const int bo = blockIdx.x >> 3;        // row tile of 32
        const int bi = blockIdx.x & 7;         // col tile of 512
#pragma unroll
        for (int v = 0; v < 8; ++v) {
            int idx = v * 256 + t;
            int r = idx >> 7;
            int c4 = idx & 127;
            reinterpret_cast<float4*>(&lAs[r][0])[c4] =
                reinterpret_cast<const float4*>(lA + (size_t)r * 4096 + bi * 512)[c4];
        }
        __syncthreads();
        const int row = t >> 3;
        const int o = bo * 32 + row;
        const float s = (float)scaling[0];
        float b[RANK];
#pragma unroll
        for (int r = 0; r < RANK; ++r) b[r] = lB[o * RANK + r] * s;
        const float* wrow = wp + (size_t)o * 1024;
        const int cbase = (t & 7) * 4;
#pragma unroll
        for (int j = 0; j < 16; ++j) {
            int c = cbase + j * 32;
            int gi = bi * 512 + c;
            float4 w = *reinterpret_cast<const float4*>(wrow + (gi & 1023));
            float a0 = w.x, a1 = w.y, a2 = w.z, a3 = w.w;
#pragma unroll
            for (int r = 0; r < RANK; ++r) {
                float4 la = *reinterpret_cast<const float4*>(&lAs[r][c]);
                a0 = fmaf(b[r], la.x, a0);
                a1 = fmaf(b[r], la.y, a1);
                a2 = fmaf(b[r], la.z, a2);
                a3 = fmaf(b[r], la.w, a3);
            }
            ushort4 ov;
            ov.x = f2bf(a0); ov.y = f2bf(a1); ov.z = f2bf(a2); ov.w = f2bf(a3);
            *reinterpret_cast<ushort4*>(weff + (size_t)o * 4096 + gi) = ov;
        }
    } else {
        const int n8 = (M_DIM * K_DIM) / 8;
        int idx = (blockIdx.x - WEFF_BLOCKS) * 256 + t;
        const int stride = CONV_BLOCKS * 256;
        for (int i = idx; i < n8; i += stride) {
            float4 v0 = reinterpret_cast<const float4*>(x)[2 * i];
            float4 v1 = reinterpret_cast<const float4*>(x)[2 * i + 1];
            u16x8 o;
            o[0] = f2bf(v0.x); o[1] = f2bf(v0.y); o[2] = f2bf(v0.z); o[3] = f2bf(v0.w);
            o[4] = f2bf(v1.x); o[5] = f2bf(v1.y); o[6] = f2bf(v1.z); o[7] = f2bf(v1.w);
            reinterpret_cast<u16x8*>(xb)[i] = o;
        }
    }
}

// ---------------- 256x256 8-phase bf16 GEMM (round-5 verified schedule) ----------------
// 10 barriers / K-pair: trailing barrier only after the vmcnt(4) phases (P4/P8).
// Hazard table (verified empirically rounds 5 + 4): every stage targets a region
// whose last read completed >= 2 phases before issue. Reg-held B frags make
// P4/P8 read-free. Direct-store epilogue (round-7, conflict-free).

template<int MH, int NH>
__device__ __forceinline__ void mfma_quad(const bf16x8 (&a)[4][2], const bf16x8 (&b)[2][2],
                                          f32x4 (&acc)[8][4]) {
#pragma unroll
    for (int kc = 0; kc < 2; ++kc)
#pragma unroll
        for (int mf = 0; mf < 4; ++mf)
#pragma unroll
            for (int nf = 0; nf < 2; ++nf)
                acc[MH * 4 + mf][NH * 2 + nf] = __builtin_amdgcn_mfma_f32_16x16x32_bf16(
                    a[mf][kc], b[nf][kc], acc[MH * 4 + mf][NH * 2 + nf], 0, 0, 0);
}

__global__ __launch_bounds__(512, 1) void gemm_kernel(
    const unsigned short* __restrict__ A,   // x bf16 [8192][4096]
    const unsigned short* __restrict__ B,   // W_eff bf16 [4096][4096]
    float* __restrict__ C)                  // [8192][4096] fp32
{
    __shared__ __align__(16) char lds[131072];

    const int tid  = threadIdx.x;
    const int lane = tid & 63;
    const int wave = tid >> 6;
    const int wr = wave >> 2;          // 0..1 (M)
    const int wc = wave & 3;           // 0..3 (N)

    // bijective XCD swizzle: 512 blocks, 8 XCDs
    const int bid = blockIdx.x;
    const int swz = (bid & 7) * 64 + (bid >> 3);
    const int bm = swz >> 4;
    const int bn = swz & 15;
    const int m0 = bm * BM;
    const int n0 = bn * BN;

    // ---- staging addressing (coalesced; pre-swizzled source col) ----
    const int srccol = 8 * ((tid & 7) ^ ((tid >> 3) & 7));
    const int wub    = (tid & ~63) * 16;                     // wave-uniform LDS byte base
    const unsigned short* Ag = A + (size_t)(m0 + (tid >> 3)) * K_DIM + srccol;
    const unsigned short* Bg = B + (size_t)(n0 + (tid >> 8) * 64 + ((tid >> 3) & 31)) * K_DIM + srccol;

#define STAGE_A(buf, mh, kt) do { \
    __builtin_amdgcn_global_load_lds( \
        (const __attribute__((address_space(1))) void*)(Ag + (size_t)((mh) * 64) * K_DIM + (size_t)(kt) * 64), \
        (__attribute__((address_space(3))) void*)(lds + (buf) * 65536 + (mh) * 16384 + wub), 16, 0, 0); \
    __builtin_amdgcn_global_load_lds( \
        (const __attribute__((address_space(1))) void*)(Ag + (size_t)(128 + (mh) * 64) * K_DIM + (size_t)(kt) * 64), \
        (__attribute__((address_space(3))) void*)(lds + (buf) * 65536 + (mh) * 16384 + 8192 + wub), 16, 0, 0); \
} while (0)

#define STAGE_B(buf, nh, kt) do { \
    __builtin_amdgcn_global_load_lds( \
        (const __attribute__((address_space(1))) void*)(Bg + (size_t)((nh) * 32) * K_DIM + (size_t)(kt) * 64), \
        (__attribute__((address_space(3))) void*)(lds + (buf) * 65536 + 32768 + (nh) * 16384 + wub), 16, 0, 0); \
    __builtin_amdgcn_global_load_lds( \
        (const __attribute__((address_space(1))) void*)(Bg + (size_t)(128 + (nh) * 32) * K_DIM + (size_t)(kt) * 64), \
        (__attribute__((address_space(3))) void*)(lds + (buf) * 65536 + 32768 + (nh) * 16384 + 8192 + wub), 16, 0, 0); \
} while (0)

    // ---- read-side addressing (16x16x32 frags) ----
    const int wrA   = wr * 8192;
    const int wcB   = wc * 4096;
    const int rdrow = (lane & 15) * 128;           // row byte offset
    const int rdxor = (lane & 7) << 4;             // swizzle XOR (row&7)<<4
    const int rdg   = (lane >> 4) * 16;            // 16B slot

#define RD_A(dst, buf, mh) do { \
    _Pragma("unroll") for (int mf = 0; mf < 4; ++mf) \
    _Pragma("unroll") for (int kc = 0; kc < 2; ++kc) \
        dst[mf][kc] = *(const bf16x8*)(lds + (buf) * 65536 + (mh) * 16384 + wrA + rdrow + mf * 2048 + ((kc * 64 + rdg) ^ rdxor)); \
} while (0)

#define RD_B(dst, buf, nh) do { \
    _Pragma("unroll") for (int nf = 0; nf < 2; ++nf) \
    _Pragma("unroll") for (int kc = 0; kc < 2; ++kc) \
        dst[nf][kc] = *(const bf16x8*)(lds + (buf) * 65536 + 32768 + (nh) * 16384 + wcB + rdrow + nf * 2048 + ((kc * 64 + rdg) ^ rdxor)); \
} while (0)

#define PH_TAIL(QUAD) \
    __builtin_amdgcn_s_barrier(); \
    asm volatile("s_waitcnt lgkmcnt(0)" ::: "memory"); \
    __builtin_amdgcn_s_setprio(1); \
    QUAD; \
    __builtin_amdgcn_s_setprio(0);

    f32x4 acc[8][4];
#pragma unroll
    for (int i = 0; i < 8; ++i)
#pragma unroll
        for (int j = 0; j < 4; ++j) acc[i][j] = (f32x4){0.f, 0.f, 0.f, 0.f};

    bf16x8 afr[4][2];
    bf16x8 b0[2][2], b1[2][2];   // register-held B frags (live across phases)

    // ---- prologue: tile0 (4 halves) + tile1 (A0,B1) ----
    STAGE_A(0, 0, 0); STAGE_B(0, 1, 0); STAGE_A(0, 1, 0); STAGE_B(0, 0, 0);
    STAGE_A(1, 0, 1); STAGE_B(1, 1, 1);
    asm volatile("s_waitcnt vmcnt(4)" ::: "memory");
    __builtin_amdgcn_s_barrier();

    for (int it = 0; it < NKT / 2; ++it) {
        const int k1 = 2 * it + 1;
        const int k2 = (2 * it + 2) & (NKT - 1);   // dummy re-stage on last iter (safe)
        const int k3 = (2 * it + 3) & (NKT - 1);

        // P1: buf0 quad(0,0)
        RD_A(afr, 0, 0); RD_B(b0, 0, 0);
        STAGE_A(1, 1, k1);
        asm volatile("s_waitcnt lgkmcnt(8)" ::: "memory");
        PH_TAIL((mfma_quad<0, 0>(afr, b0, acc)));
        // P2: buf0 quad(0,1)
        RD_B(b1, 0, 1);
        STAGE_B(1, 0, k1);
        PH_TAIL((mfma_quad<0, 1>(afr, b1, acc)));
        // P3: buf0 quad(1,1)
        RD_A(afr, 0, 1);
        STAGE_A(0, 0, k2);
        PH_TAIL((mfma_quad<1, 1>(afr, b1, acc)));
        // P4: buf0 quad(1,0) — read-free; counted vmcnt + barrier (buf1-k1 landed)
        STAGE_B(0, 1, k2);
        PH_TAIL((mfma_quad<1, 0>(afr, b0, acc)));
        asm volatile("s_waitcnt vmcnt(4)" ::: "memory");
        __builtin_amdgcn_s_barrier();
        // P5: buf1 quad(0,0)
        RD_A(afr, 1, 0); RD_B(b0, 1, 0);
        STAGE_A(0, 1, k2);
        asm volatile("s_waitcnt lgkmcnt(8)" ::: "memory");
        PH_TAIL((mfma_quad<0, 0>(afr, b0, acc)));
        // P6: buf1 quad(0,1)
        RD_B(b1, 1, 1);
        STAGE_B(0, 0, k2);
        PH_TAIL((mfma_quad<0, 1>(afr, b1, acc)));
        // P7: buf1 quad(1,1)
        RD_A(afr, 1, 1);
        STAGE_A(1, 0, k3);
        PH_TAIL((mfma_quad<1, 1>(afr, b1, acc)));
        // P8: buf1 quad(1,0) — read-free; counted vmcnt + barrier (buf0-k2 landed)
        STAGE_B(1, 1, k3);
        PH_TAIL((mfma_quad<1, 0>(afr, b0, acc)));
        asm volatile("s_waitcnt vmcnt(4)" ::: "memory");
        __builtin_amdgcn_s_barrier();
    }

    // ---- epilogue: direct stores. D frag: col = lane&15, row = (lane>>4)*4 + r ----
    const int crow = m0 + wr * 128 + (lane >> 4) * 4;
    const int ccol = n0 + wc * 64 + (lane & 15);
#pragma unroll
    for (int mi = 0; mi < 8; ++mi)
#pragma unroll
        for (int ni = 0; ni < 4; ++ni)
#pragma unroll
            for (int r = 0; r < 4; ++r)
                C[(size_t)(crow + mi * 16 + r) * N_DIM + ccol + ni * 16] = acc[mi][ni][r];

#undef STAGE_A
#undef STAGE_B
#undef RD_A
#undef RD_B
#undef PH_TAIL
}

extern "C" void kernel_launch(void* const* d_in, const int* in_sizes, int n_in,
                              void* d_out, int out_size, void* d_ws, size_t ws_size,
                              hipStream_t stream) {
    const float* x  = (const float*)d_in[0];
    const float* wp = (const float*)d_in[1];
    const float* lA = (const float*)d_in[2];
    const float* lB = (const float*)d_in[3];
    const int*   sc = (const int*)d_in[4];
    float* out = (float*)d_out;

    unsigned short* xb   = (unsigned short*)d_ws;                               // 64 MB
    unsigned short* weff = (unsigned short*)d_ws + (size_t)M_DIM * K_DIM;       // 32 MB

    prep_kernel<<<WEFF_BLOCKS + CONV_BLOCKS, 256, 0, stream>>>(x, wp, lA, lB, sc, xb, weff);

    int grid = (M_DIM / BM) * (N_DIM / BN);   // 32 * 16 = 512
    gemm_kernel<<<grid, 512, 0, stream>>>(xb, weff, out);
}